// Round 3
// baseline (226.197 us; speedup 1.0000x reference)
//
#include <hip/hip_runtime.h>
#include <hip/hip_bf16.h>
#include <cstdint>
#include <math.h>

// Problem constants
#define SEQ    2048
#define DMODEL 1024
#define NHEAD  16
#define DHEAD  64

typedef __bf16 bf16;
typedef __bf16 bf16x8 __attribute__((ext_vector_type(8)));
typedef float  f32x4  __attribute__((ext_vector_type(4)));

typedef __attribute__((address_space(3))) uint32_t lds_u32;
typedef __attribute__((address_space(1))) const uint32_t global_u32;

__device__ __forceinline__ void async_load16(const void* g, void* l) {
    __builtin_amdgcn_global_load_lds((global_u32*)g, (lds_u32*)l, 16, 0, 0);
}

// ---------------------------------------------------------------------------
// Merged preprocessing:
//   [0,3072)        fp32->bf16 cast of q/k/v activations
//   [3072,7168)     W[K][N] fp32 -> WT[N][K] bf16 for wq/wk/wv/wo
//   [7168,15360)    zero fp32 accumulators qp/kp/vp/out (split-K atomic targets)
#define CAST_BLOCKS 3072
#define TR_BLOCKS   4096
#define ZERO_BLOCKS 8192

__global__ __launch_bounds__(256) void prep_kernel(
    const float* __restrict__ q, const float* __restrict__ k, const float* __restrict__ v,
    bf16* __restrict__ qx, bf16* __restrict__ kx, bf16* __restrict__ vx,
    const float* __restrict__ w0, const float* __restrict__ w1,
    const float* __restrict__ w2, const float* __restrict__ w3,
    bf16* __restrict__ t0, bf16* __restrict__ t1,
    bf16* __restrict__ t2, bf16* __restrict__ t3,
    float* __restrict__ qp, float* __restrict__ kp, float* __restrict__ vp,
    float* __restrict__ out) {
    __shared__ float tile[32][33];
    const int bid = blockIdx.x;
    if (bid < CAST_BLOCKS) {
        const int z = bid >> 10;
        const float* src = (z == 0) ? q : (z == 1) ? k : v;
        bf16* dst        = (z == 0) ? qx : (z == 1) ? kx : vx;
        const int i = (bid & 1023) * 256 + threadIdx.x;
        const float4* s4 = (const float4*)src;
        float4 a = s4[i * 2 + 0];
        float4 b = s4[i * 2 + 1];
        bf16x8 o;
        o[0] = (bf16)a.x; o[1] = (bf16)a.y; o[2] = (bf16)a.z; o[3] = (bf16)a.w;
        o[4] = (bf16)b.x; o[5] = (bf16)b.y; o[6] = (bf16)b.z; o[7] = (bf16)b.w;
        ((bf16x8*)dst)[i] = o;
    } else if (bid < CAST_BLOCKS + TR_BLOCKS) {
        const int b = bid - CAST_BLOCKS;
        const int z = b >> 10, rem = b & 1023;
        const float* w = (z == 0) ? w0 : (z == 1) ? w1 : (z == 2) ? w2 : w3;
        bf16* t        = (z == 0) ? t0 : (z == 1) ? t1 : (z == 2) ? t2 : t3;
        const int tx = threadIdx.x & 31, ty = threadIdx.x >> 5;
        const int kbase = (rem >> 5) * 32, nbase = (rem & 31) * 32;
#pragma unroll
        for (int i = 0; i < 4; ++i)
            tile[ty + 8 * i][tx] = w[(size_t)(kbase + ty + 8 * i) * DMODEL + nbase + tx];
        __syncthreads();
#pragma unroll
        for (int i = 0; i < 4; ++i)
            t[(size_t)(nbase + ty + 8 * i) * DMODEL + kbase + tx] = (bf16)tile[tx][ty + 8 * i];
    } else {
        // zero 4 fp32 arrays of 2M elems each: 2M float4 total
        const int zb = bid - CAST_BLOCKS - TR_BLOCKS;
        const int f = zb * 256 + threadIdx.x;            // float4 index
        const int arr = f >> 19;                          // 524288 float4 per array
        const int off = f & 524287;
        float* dst = (arr == 0) ? qp : (arr == 1) ? kp : (arr == 2) ? vp : out;
        ((float4*)dst)[off] = make_float4(0.f, 0.f, 0.f, 0.f);
    }
}

// ---------------------------------------------------------------------------
// Split-K GEMM tile: C[M][1024] += A[M][1024] @ BT[1024][1024]^T (+bias on
// split 0), bf16 MFMA 16x16x32, 128x128 tile, m97 staging structure,
// fp32 atomicAdd epilogue into pre-zeroed C.
__device__ __forceinline__ void gemm_bt_atomic_body(
    const bf16* __restrict__ A, const bf16* __restrict__ BT,
    const float* __restrict__ bias, float* __restrict__ C,
    int kbase, int ksize, bool addb) {
    constexpr int K = 1024, N = 1024;
    __shared__ bf16 sA[128 * 32];
    __shared__ bf16 sB[128 * 32];
    const int tid = threadIdx.x;
    const int w = tid >> 6, lane = tid & 63;
    const int wm = w >> 1, wn = w & 1;
    const int lr = lane & 15, quad = lane >> 4;
    const int m0 = blockIdx.y * 128, n0 = blockIdx.x * 128;

    f32x4 acc[4][4] = {};
    float bia[4];
#pragma unroll
    for (int ni = 0; ni < 4; ++ni) bia[ni] = addb ? bias[n0 + wn * 64 + ni * 16 + lr] : 0.f;

    for (int kt = kbase; kt < kbase + ksize; kt += 32) {
#pragma unroll
        for (int r = 0; r < 2; ++r) {
            const int c = r * 256 + w * 64 + lane;
            const int row = c >> 2, ch = c & 3;
            const bf16* ga = A + (size_t)(m0 + row) * K + kt + ch * 8;
            const bf16* gb = BT + (size_t)(n0 + row) * K + kt + ch * 8;
            char* la = (char*)sA + (r * 256 + w * 64) * 16;
            char* lb = (char*)sB + (r * 256 + w * 64) * 16;
            async_load16(ga, la);
            async_load16(gb, lb);
        }
        __syncthreads();

        bf16x8 af[4], bfr[4];
#pragma unroll
        for (int mi = 0; mi < 4; ++mi)
            af[mi] = *(const bf16x8*)&sA[(wm * 64 + mi * 16 + lr) * 32 + quad * 8];
#pragma unroll
        for (int ni = 0; ni < 4; ++ni)
            bfr[ni] = *(const bf16x8*)&sB[(wn * 64 + ni * 16 + lr) * 32 + quad * 8];
#pragma unroll
        for (int mi = 0; mi < 4; ++mi)
#pragma unroll
            for (int ni = 0; ni < 4; ++ni)
                acc[mi][ni] = __builtin_amdgcn_mfma_f32_16x16x32_bf16(
                    af[mi], bfr[ni], acc[mi][ni], 0, 0, 0);
        __syncthreads();
    }

#pragma unroll
    for (int mi = 0; mi < 4; ++mi)
#pragma unroll
        for (int ni = 0; ni < 4; ++ni) {
            const int row = m0 + wm * 64 + mi * 16 + quad * 4;
            const int col = n0 + wn * 64 + ni * 16 + lr;
            const f32x4 vv = acc[mi][ni];
#pragma unroll
            for (int r = 0; r < 4; ++r)
                atomicAdd(&C[(size_t)(row + r) * N + col], vv[r] + bia[ni]);
        }
}

// q/k/v projections, split-K x2: z = proj*2 + khalf -> 768 blocks (3/CU)
__global__ __launch_bounds__(256) void proj3_kernel(
    const bf16* qx, const bf16* kx, const bf16* vx,
    const bf16* wqT, const bf16* wkT, const bf16* wvT,
    const float* bq, const float* bk, const float* bv,
    float* qp, float* kp, float* vp) {
    const int z = blockIdx.z;
    const int proj = z >> 1, split = z & 1;
    const bf16* A  = (proj == 0) ? qx : (proj == 1) ? kx : vx;
    const bf16* BT = (proj == 0) ? wqT : (proj == 1) ? wkT : wvT;
    const float* b = (proj == 0) ? bq : (proj == 1) ? bk : bv;
    float* C       = (proj == 0) ? qp : (proj == 1) ? kp : vp;
    gemm_bt_atomic_body(A, BT, b, C, split * 512, 512, split == 0);
}

// output projection, split-K x4 -> 512 blocks (2/CU)
__global__ __launch_bounds__(256) void gemm_final_kernel(
    const bf16* A, const bf16* BT, const float* bias, float* C) {
    const int split = blockIdx.z;
    gemm_bt_atomic_body(A, BT, bias, C, split * 256, 256, split == 0);
}

// ---------------------------------------------------------------------------
// Sparse attention with ANALYTIC layout (no layout read, no index arrays).
// Grid (T,H,W)=(8,16,16): row s's support = local {s-3..s} ∪ axial-T
// {tt*256 + s%256, tt<=T} ∪ axial-H {T*256 + hh*16 + W, hh<=H}; the three
// sets overlap only at s itself => cnt = min(s,3)+1 + T + H  (max 26).
__global__ __launch_bounds__(256) void attn_kernel(
    const float* __restrict__ qp, const float* __restrict__ kp, const float* __restrict__ vp,
    bf16* __restrict__ ao) {
    const int wv = threadIdx.x >> 6, lane = threadIdx.x & 63;
    const int p = blockIdx.x * 4 + wv;
    const int s = __builtin_amdgcn_readfirstlane(p & (SEQ - 1));
    const int h = __builtin_amdgcn_readfirstlane(p >> 11);
    const int hoff = h * DHEAD + lane;

    const int sT = s >> 8, sH = (s >> 4) & 15;
    const int sLow = s & 255, sTop = s & ~255, sW = s & 15;
    const int L = ((s < 3) ? s : 3) + 1;
    const int cnt = L + sT + sH;
    auto nz_t = [&](int c) -> int {
        return (c < L) ? (s - c)
             : (c < L + sT) ? (((c - L) << 8) + sLow)
             : (c < cnt) ? (sTop + ((c - L - sT) << 4) + sW)
             : s;  // padded slot (masked)
    };

    const float q = qp[(size_t)s * DMODEL + hoff];

    // 32 independent K-row loads + per-lane partial products
    float pr[32];
#pragma unroll
    for (int c = 0; c < 32; ++c)
        pr[c] = q * kp[(size_t)nz_t(c) * DMODEL + hoff];

    // 5-step tree transpose-reduce: lane l ends with full dot for c = l&31
#pragma unroll
    for (int step = 0; step < 5; ++step) {
        const int mask = 1 << step;
        const int half = 32 >> (step + 1);
        const bool hi = (lane & mask) != 0;
#pragma unroll
        for (int c = 0; c < half; ++c) {
            const float a = pr[2 * c], b = pr[2 * c + 1];
            const float mine = hi ? b : a;
            const float oth  = hi ? a : b;
            pr[c] = mine + __shfl_xor(oth, mask);
        }
    }
    const float dotv = pr[0] + __shfl_xor(pr[0], 32);

    const int c_lane = lane & 31;
    const float logit = (c_lane < cnt) ? dotv * 0.125f : -1e30f;  // 1/sqrt(64)
    float m = logit;
    m = fmaxf(m, __shfl_xor(m, 1)); m = fmaxf(m, __shfl_xor(m, 2));
    m = fmaxf(m, __shfl_xor(m, 4)); m = fmaxf(m, __shfl_xor(m, 8));
    m = fmaxf(m, __shfl_xor(m, 16));
    const float e = __expf(logit - m);
    float ssum = e;
    ssum += __shfl_xor(ssum, 1); ssum += __shfl_xor(ssum, 2);
    ssum += __shfl_xor(ssum, 4); ssum += __shfl_xor(ssum, 8);
    ssum += __shfl_xor(ssum, 16);
    const float prob = e / ssum;

    float acc = 0.f;
#pragma unroll
    for (int c = 0; c < 32; ++c)
        acc += __shfl(prob, c) * vp[(size_t)nz_t(c) * DMODEL + hoff];
    ao[(size_t)s * DMODEL + hoff] = (bf16)acc;
}

// ---------------------------------------------------------------------------
extern "C" void kernel_launch(void* const* d_in, const int* in_sizes, int n_in,
                              void* d_out, int out_size, void* d_ws, size_t ws_size,
                              hipStream_t stream) {
    const float* query = (const float*)d_in[0];
    const float* key   = (const float*)d_in[1];
    const float* value = (const float*)d_in[2];
    const float* wq = (const float*)d_in[3];
    const float* bq = (const float*)d_in[4];
    const float* wk = (const float*)d_in[5];
    const float* bk = (const float*)d_in[6];
    const float* wv = (const float*)d_in[7];
    const float* bv = (const float*)d_in[8];
    const float* wo = (const float*)d_in[9];
    const float* bo = (const float*)d_in[10];
    float* out = (float*)d_out;

    char* ws = (char*)d_ws;
    auto alloc = [&](size_t bytes) {
        char* p = ws;
        ws += (bytes + 255) & ~(size_t)255;
        return p;
    };
    bf16* qx  = (bf16*)alloc((size_t)SEQ * DMODEL * 2);
    bf16* kx  = (bf16*)alloc((size_t)SEQ * DMODEL * 2);
    bf16* vx  = (bf16*)alloc((size_t)SEQ * DMODEL * 2);
    bf16* wqT = (bf16*)alloc((size_t)DMODEL * DMODEL * 2);
    bf16* wkT = (bf16*)alloc((size_t)DMODEL * DMODEL * 2);
    bf16* wvT = (bf16*)alloc((size_t)DMODEL * DMODEL * 2);
    bf16* woT = (bf16*)alloc((size_t)DMODEL * DMODEL * 2);
    float* qp = (float*)alloc((size_t)SEQ * DMODEL * 4);   // fp32 split-K accum
    float* kp = (float*)alloc((size_t)SEQ * DMODEL * 4);
    float* vp = (float*)alloc((size_t)SEQ * DMODEL * 4);
    bf16* ao  = (bf16*)alloc((size_t)SEQ * DMODEL * 2);

    // 1. prep: casts + weight transposes + zero the atomic accumulators
    prep_kernel<<<dim3(CAST_BLOCKS + TR_BLOCKS + ZERO_BLOCKS), 256, 0, stream>>>(
        query, key, value, qx, kx, vx,
        wq, wk, wv, wo, wqT, wkT, wvT, woT,
        qp, kp, vp, out);
    // 2. q/k/v projections, split-K x2: 768 blocks = 3/CU
    proj3_kernel<<<dim3(8, 16, 6), 256, 0, stream>>>(
        qx, kx, vx, wqT, wkT, wvT, bq, bk, bv, qp, kp, vp);
    // 3. sparse attention (analytic layout)
    attn_kernel<<<dim3(NHEAD * SEQ / 4), 256, 0, stream>>>(qp, kp, vp, ao);
    // 4. output projection, split-K x4: 512 blocks = 2/CU
    gemm_final_kernel<<<dim3(8, 16, 4), 256, 0, stream>>>(ao, woT, bo, out);
}